// Round 10
// baseline (289.961 us; speedup 1.0000x reference)
//
#include <hip/hip_runtime.h>

#define C_IN 256
#define C_OUT 64
#define BSH 7                 // bucket = dst >> 7  (128 nodes/bucket)
#define NPB 128               // nodes per bucket
#define NB 1024               // max buckets (n <= 131072)
#define CHUNK 8192            // edges per binning block (LDS-staged multisplit)
#define RG 32                 // rows per row-group in kA2 (16*32=512 >= nbin=391)
#define SCAP 6144             // k_sort2 LDS stage capacity (lambda=4096, 32 sigma margin)

typedef short bf16x8 __attribute__((ext_vector_type(8)));
typedef float f32x4 __attribute__((ext_vector_type(4)));

__device__ __forceinline__ unsigned short f2bf(float f) {
    unsigned u = __builtin_bit_cast(unsigned, f);
    u = (u + 0x7FFFu + ((u >> 16) & 1u)) >> 16;
    return (unsigned short)u;
}
__device__ __forceinline__ float bflo(unsigned u) {
    return __builtin_bit_cast(float, u << 16);
}
__device__ __forceinline__ float bfhi(unsigned u) {
    return __builtin_bit_cast(float, u & 0xffff0000u);
}

// ---------------- one-shot: WTs = bf16(W^T) in XOR-swizzled LDS layout ----------------
__global__ __launch_bounds__(256) void k_wt(const float* __restrict__ W,
                                            unsigned short* __restrict__ WTs) {
#pragma unroll
    for (int i = 0; i < 16; ++i) {
        int f = i * 256 + threadIdx.x;   // float4 id over 256x64
        int k = f >> 4;
        int n4 = (f & 15) * 4;
        float4 v = ((const float4*)W)[f];
        int c = k >> 3, ci = k & 7;
        float vv[4] = {v.x, v.y, v.z, v.w};
#pragma unroll
        for (int r = 0; r < 4; ++r) {
            int row = n4 + r;
            WTs[row * 256 + ((c ^ (row & 7)) << 3) + ci] = f2bf(vv[r]);
        }
    }
}

// ---------------- per-(block,bucket) histogram table: table[bin][bucket] ----------------
__global__ __launch_bounds__(1024) void k_hist2(const int* __restrict__ dst,
                                                int* __restrict__ table, int e) {
    __shared__ int cnt[NB];
    cnt[threadIdx.x] = 0;
    __syncthreads();
    int b0 = blockIdx.x * CHUNK;
#pragma unroll
    for (int k = 0; k < CHUNK / 1024; ++k) {
        int i = b0 + k * 1024 + threadIdx.x;
        if (i < e) atomicAdd(&cnt[dst[i] >> BSH], 1);
    }
    __syncthreads();
    table[(size_t)blockIdx.x * NB + threadIdx.x] = cnt[threadIdx.x];
}

// ---------------- column-wise exclusive scan, line-coalesced ----------------
__global__ __launch_bounds__(256) void kA2(int* __restrict__ table,
                                           int* __restrict__ tot, int nbin) {
    __shared__ int part[256];
    int t = threadIdx.x;
    int bc = t & 15, rg = t >> 4;
    int B = blockIdx.x * 16 + bc;
    int v[RG];
    int s = 0;
#pragma unroll
    for (int i = 0; i < RG; ++i) {
        int r = rg * RG + i;
        int x = (r < nbin) ? table[(size_t)r * NB + B] : 0;
        v[i] = s;
        s += x;
    }
    part[t] = s;
    __syncthreads();
#pragma unroll
    for (int off = 1; off < 16; off <<= 1) {
        int u = (rg >= off) ? part[t - off * 16] : 0;
        __syncthreads();
        part[t] += u;
        __syncthreads();
    }
    int incl = part[t];
    int base = incl - s;   // exclusive over row-groups
#pragma unroll
    for (int i = 0; i < RG; ++i) {
        int r = rg * RG + i;
        if (r < nbin) table[(size_t)r * NB + B] = base + v[i];
    }
    if (rg == 15) tot[B] = incl;
}

// ---------------- bucket totals -> compact gbase ----------------
__global__ __launch_bounds__(1024) void kB(const int* __restrict__ tot,
                                           int* __restrict__ gbase, int e) {
    __shared__ int l[NB];
    int t = threadIdx.x;
    int v = tot[t];
    l[t] = v;
    __syncthreads();
    for (int off = 1; off < NB; off <<= 1) {
        int u = (t >= off) ? l[t - off] : 0;
        __syncthreads();
        l[t] += u;
        __syncthreads();
    }
    gbase[t] = l[t] - v;  // exclusive
    if (t == NB - 1) gbase[NB] = e;
}

// ---------------- LDS-staged multisplit: bucket-contiguous coalesced writes ----------------
__global__ __launch_bounds__(1024) void k_bin2(const int* __restrict__ src,
                                               const int* __restrict__ dst,
                                               const int* __restrict__ table,
                                               const int* __restrict__ gbase,
                                               int* __restrict__ sorted, int e) {
    __shared__ int stage[CHUNK];            // 32 KB: packed values, bucket-sorted
    __shared__ unsigned short sbkt[CHUNK];  // 16 KB: bucket tag per stage slot
    __shared__ int lcnt[NB];                // counts, later reused as global base
    __shared__ int lsc[NB];                 // inclusive scan
    __shared__ int lbase[NB];               // exclusive scan
    int t = threadIdx.x;
    lcnt[t] = 0;
    __syncthreads();
    int b0 = blockIdx.x * CHUNK;

    int bb[CHUNK / 1024], pv[CHUNK / 1024], rk[CHUNK / 1024];
#pragma unroll
    for (int k = 0; k < CHUNK / 1024; ++k) {
        int i = b0 + k * 1024 + t;
        if (i < e) {
            int d = dst[i];
            bb[k] = d >> BSH;
            pv[k] = (src[i] << BSH) | (d & (NPB - 1));
            rk[k] = atomicAdd(&lcnt[bb[k]], 1);   // rank within (block,bucket)
        } else {
            bb[k] = -1;
        }
    }
    __syncthreads();
    lsc[t] = lcnt[t];
    __syncthreads();
    for (int off = 1; off < NB; off <<= 1) {
        int u = (t >= off) ? lsc[t - off] : 0;
        __syncthreads();
        lsc[t] += u;
        __syncthreads();
    }
    lbase[t] = lsc[t] - lcnt[t];
    __syncthreads();
    int tot = lsc[NB - 1];

    // scatter into LDS stage (bucket-sorted); also pre-load global bases
#pragma unroll
    for (int k = 0; k < CHUNK / 1024; ++k) {
        if (bb[k] >= 0) {
            int p = lbase[bb[k]] + rk[k];
            stage[p] = pv[k];
            sbkt[p] = (unsigned short)bb[k];
        }
    }
    lcnt[t] = gbase[t] + table[(size_t)blockIdx.x * NB + t];  // reuse as gb[bucket]
    __syncthreads();

    // coalesced sweep: consecutive j in same bucket -> consecutive global addrs
#pragma unroll
    for (int k = 0; k < CHUNK / 1024; ++k) {
        int j = k * 1024 + t;
        if (j < tot) {
            int B = sbkt[j];
            sorted[lcnt[B] + (j - lbase[B])] = stage[j];
        }
    }
}

// ---------------- in-bucket counting sort -> per-node CSR, plus dinv (512 thr) ----------------
__global__ __launch_bounds__(512) void k_sort2(const int* __restrict__ sorted,
                                               const int* __restrict__ gbase,
                                               int* __restrict__ eidx,
                                               int* __restrict__ rowptr,
                                               float* __restrict__ dinv, int n, int e) {
    __shared__ int cnt[NPB];
    __shared__ int sc[NPB];
    __shared__ int cur[NPB];
    __shared__ int sstage[SCAP];   // 24 KB
    int b = blockIdx.x;
    int node0 = b * NPB;
    int range = min(NPB, n - node0);
    int inbase = gbase[b];
    int m_b = gbase[b + 1] - inbase;
    bool fits = (m_b <= SCAP);
    if (threadIdx.x < NPB) cnt[threadIdx.x] = 0;
    if (fits)
        for (int j = threadIdx.x; j < m_b; j += 512) sstage[j] = sorted[inbase + j];
    __syncthreads();
    for (int j = threadIdx.x; j < m_b; j += 512) {
        int v = fits ? sstage[j] : sorted[inbase + j];
        atomicAdd(&cnt[v & (NPB - 1)], 1);
    }
    __syncthreads();
    if (threadIdx.x < NPB) sc[threadIdx.x] = cnt[threadIdx.x];
    __syncthreads();
    for (int off = 1; off < NPB; off <<= 1) {
        int t = (threadIdx.x < NPB && threadIdx.x >= off) ? sc[threadIdx.x - off] : 0;
        __syncthreads();
        if (threadIdx.x < NPB) sc[threadIdx.x] += t;
        __syncthreads();
    }
    if (threadIdx.x < NPB) {
        int excl = inbase + sc[threadIdx.x] - cnt[threadIdx.x];
        cur[threadIdx.x] = excl;
        if (threadIdx.x < range) {
            rowptr[node0 + threadIdx.x] = excl;
            dinv[node0 + threadIdx.x] = rsqrtf((float)(cnt[threadIdx.x] + 1));
        }
    }
    __syncthreads();
    for (int j = threadIdx.x; j < m_b; j += 512) {
        int v = fits ? sstage[j] : sorted[inbase + j];
        int pos = atomicAdd(&cur[v & (NPB - 1)], 1);
        eidx[pos] = v >> BSH;
    }
    if (b == 0 && threadIdx.x == 0) rowptr[n] = e;
}

// ---------------- h' = (x @ W) * dinv[row], bf16 MFMA (R6/R7 form -- best measured) ----------------
__global__ __launch_bounds__(256, 3) void k_gemm(const float* __restrict__ x,
                                                 const unsigned short* __restrict__ WTs,
                                                 const float* __restrict__ dinv,
                                                 unsigned short* __restrict__ h, int n) {
    __shared__ unsigned short Wl[64 * 256];   // 32 KB, swizzled content, linear layout

    const int t = threadIdx.x;
    const int lane = t & 63;
    const int wv = t >> 6;      // wave 0..3 -> A rows 16wv..16wv+15
    const int m = lane & 15;
    const int q = lane >> 4;
    const int mx = m & 7;

    // zero pad row h[n] (128 B) for k_gather's padded gathers
    if (blockIdx.x == 0 && t < 8)
        *(uint4*)&h[(size_t)n * C_OUT + t * 8] = make_uint4(0u, 0u, 0u, 0u);

    // -------- stage WTs -> Wl: 8 async direct-to-LDS copies
#pragma unroll
    for (int j = 0; j < 8; ++j) {
        const unsigned short* gsrc = WTs + j * 2048 + wv * 512 + lane * 8;  // 16 B/lane
        unsigned short* ldst = Wl + j * 2048 + wv * 512;                    // wave-uniform
        __builtin_amdgcn_global_load_lds(
            (const __attribute__((address_space(1))) unsigned int*)gsrc,
            (__attribute__((address_space(3))) unsigned int*)ldst, 16, 0, 0);
    }

    // -------- issue ALL 16 x-loads (inline asm: compiler cannot fold/serialize)
    int arow = blockIdx.x * 64 + 16 * wv + m;
    const float* xp = x + (size_t)(arow < n ? arow : 0) * C_IN + q * 8;
    float4 raw[16];
#pragma unroll
    for (int ks = 0; ks < 8; ++ks) {
        const float* p0 = xp + ks * 32;
        const float* p1 = xp + ks * 32 + 4;
        asm volatile("global_load_dwordx4 %0, %1, off" : "=v"(raw[2 * ks]) : "v"(p0));
        asm volatile("global_load_dwordx4 %0, %1, off" : "=v"(raw[2 * ks + 1]) : "v"(p1));
    }

    // -------- single drain point for x-loads AND the LDS staging
    asm volatile("s_waitcnt vmcnt(0)" ::: "memory");
    __builtin_amdgcn_sched_barrier(0);
    __syncthreads();

    float di[4];
#pragma unroll
    for (int r = 0; r < 4; ++r) {
        int gr = blockIdx.x * 64 + 16 * wv + q * 4 + r;
        di[r] = dinv[gr < n ? gr : 0];
    }

    bf16x8 A[8];
#pragma unroll
    for (int ks = 0; ks < 8; ++ks) {
        float4 v0 = raw[2 * ks];
        float4 v1 = raw[2 * ks + 1];
        bf16x8 a;
        a[0] = (short)f2bf(v0.x); a[1] = (short)f2bf(v0.y);
        a[2] = (short)f2bf(v0.z); a[3] = (short)f2bf(v0.w);
        a[4] = (short)f2bf(v1.x); a[5] = (short)f2bf(v1.y);
        a[6] = (short)f2bf(v1.z); a[7] = (short)f2bf(v1.w);
        A[ks] = a;
    }

    f32x4 acc[4];
#pragma unroll
    for (int nt = 0; nt < 4; ++nt) acc[nt] = (f32x4){0.f, 0.f, 0.f, 0.f};

#pragma unroll
    for (int ks = 0; ks < 8; ++ks) {
        int cs = ((ks * 4 + q) ^ mx) << 3;   // XOR-swizzled 16B slot within row
#pragma unroll
        for (int nt = 0; nt < 4; ++nt) {
            bf16x8 B = *(const bf16x8*)&Wl[(nt * 16 + m) * 256 + cs];
            acc[nt] = __builtin_amdgcn_mfma_f32_16x16x32_bf16(A[ks], B, acc[nt], 0, 0, 0);
        }
    }

#pragma unroll
    for (int r = 0; r < 4; ++r) {
        int gr = blockIdx.x * 64 + 16 * wv + q * 4 + r;
        if (gr < n) {
#pragma unroll
            for (int nt = 0; nt < 4; ++nt)
                h[(size_t)gr * C_OUT + nt * 16 + m] = f2bf(acc[nt][r] * di[r]);
        }
    }
}

// ---------------- gather: 1 wave/node, always-8 batched gathers ----------------
#define GROUND(T, HV)                                                                   \
    {                                                                                   \
        int s_ = __shfl(eid, (T) * 8 + g, 64);                                          \
        const unsigned short* p_ = h + (size_t)s_ * C_OUT + c8;                         \
        asm volatile("global_load_dwordx4 %0, %1, off" : "=v"(HV) : "v"(p_));           \
    }
#define ACC8(HV)                                                                        \
    {                                                                                   \
        a0 += bflo(HV.x); a1 += bfhi(HV.x); a2 += bflo(HV.y); a3 += bfhi(HV.y);         \
        a4 += bflo(HV.z); a5 += bfhi(HV.z); a6 += bflo(HV.w); a7 += bfhi(HV.w);         \
    }

__global__ __launch_bounds__(256, 6) void k_gather(const int* __restrict__ rowptr,
                                                   const int* __restrict__ eidx,
                                                   const unsigned short* __restrict__ h,
                                                   const float* __restrict__ dinv,
                                                   const float* __restrict__ bias,
                                                   float* __restrict__ out, int n) {
    int node = blockIdx.x * 4 + (threadIdx.x >> 6);
    if (node >= n) return;
    int lane = threadIdx.x & 63;
    int g = lane >> 3;          // edge slot group 0..7
    int c8 = (lane & 7) * 8;    // channel base 0..56

    int beg = rowptr[node];
    int end = rowptr[node + 1];

    float a0 = 0.f, a1 = 0.f, a2 = 0.f, a3 = 0.f;
    float a4 = 0.f, a5 = 0.f, a6 = 0.f, a7 = 0.f;

    // -------- 64-edge batches: one wave-wide eidx load, 8 gathers always in flight
    for (int j = beg; j < end; j += 64) {
        int idx = j + lane;
        int eid = (idx < end) ? eidx[idx] : n;   // pad -> zero row (L1-hot)
        uint4 hv0, hv1, hv2, hv3, hv4, hv5, hv6, hv7;
        GROUND(0, hv0); GROUND(1, hv1); GROUND(2, hv2); GROUND(3, hv3);
        GROUND(4, hv4); GROUND(5, hv5); GROUND(6, hv6); GROUND(7, hv7);
        asm volatile("s_waitcnt vmcnt(0)" ::: "memory");
        __builtin_amdgcn_sched_barrier(0);
        ACC8(hv0); ACC8(hv1); ACC8(hv2); ACC8(hv3);
        ACC8(hv4); ACC8(hv5); ACC8(hv6); ACC8(hv7);
    }

#pragma unroll
    for (int off = 8; off < 64; off <<= 1) {
        a0 += __shfl_xor(a0, off, 64); a1 += __shfl_xor(a1, off, 64);
        a2 += __shfl_xor(a2, off, 64); a3 += __shfl_xor(a3, off, 64);
        a4 += __shfl_xor(a4, off, 64); a5 += __shfl_xor(a5, off, 64);
        a6 += __shfl_xor(a6, off, 64); a7 += __shfl_xor(a7, off, 64);
    }
    if (g == 0) {
        float di = dinv[node];
        uint4 sv = *(const uint4*)&h[(size_t)node * C_OUT + c8];
        float4 b0 = *(const float4*)&bias[c8];
        float4 b1 = *(const float4*)&bias[c8 + 4];
        float4 o0, o1;
        o0.x = (a0 + bflo(sv.x)) * di + b0.x;
        o0.y = (a1 + bfhi(sv.x)) * di + b0.y;
        o0.z = (a2 + bflo(sv.y)) * di + b0.z;
        o0.w = (a3 + bfhi(sv.y)) * di + b0.w;
        o1.x = (a4 + bflo(sv.z)) * di + b1.x;
        o1.y = (a5 + bfhi(sv.z)) * di + b1.y;
        o1.z = (a6 + bflo(sv.w)) * di + b1.z;
        o1.w = (a7 + bfhi(sv.w)) * di + b1.w;
        *(float4*)&out[(size_t)node * C_OUT + c8] = o0;
        *(float4*)&out[(size_t)node * C_OUT + c8 + 4] = o1;
    }
}

extern "C" void kernel_launch(void* const* d_in, const int* in_sizes, int n_in,
                              void* d_out, int out_size, void* d_ws, size_t ws_size,
                              hipStream_t stream) {
    const float* x = (const float*)d_in[0];
    const int* ei = (const int*)d_in[1];
    const float* W = (const float*)d_in[2];
    const float* bias = (const float*)d_in[3];
    float* out = (float*)d_out;

    const int n = in_sizes[0] / C_IN;  // 100000
    const int e = in_sizes[1] / 2;     // 3200000
    const int* src = ei;
    const int* dst = ei + e;

    const int nbin = (e + CHUNK - 1) / CHUNK;   // 391 (<= 16*RG = 512)
    const int nbuck = (n + NPB - 1) / NPB;      // 782

    char* w = (char*)d_ws;
    unsigned short* h = (unsigned short*)w;  w += ((size_t)n + 1) * C_OUT * 2; // 12.8 MB + pad row
    int* sorted = (int*)w;                   w += (size_t)e * 4;           // 12.8 MB
    int* eidx = (int*)w;                     w += (size_t)e * 4;           // 12.8 MB
    float* dinv = (float*)w;                 w += (size_t)n * 4;
    int* rowptr = (int*)w;                   w += (size_t)(n + 1) * 4;
    int* table = (int*)w;                    w += (size_t)nbin * NB * 4;   // 1.6 MB
    int* tot = (int*)w;                      w += NB * 4;
    int* gbase = (int*)w;                    w += (NB + 1) * 4;
    unsigned short* WTs = (unsigned short*)w; w += (size_t)C_OUT * C_IN * 2; // 32 KB

    k_wt<<<1, 256, 0, stream>>>(W, WTs);
    k_hist2<<<nbin, 1024, 0, stream>>>(dst, table, e);
    kA2<<<NB / 16, 256, 0, stream>>>(table, tot, nbin);
    kB<<<1, 1024, 0, stream>>>(tot, gbase, e);
    k_bin2<<<nbin, 1024, 0, stream>>>(src, dst, table, gbase, sorted, e);
    k_sort2<<<nbuck, 512, 0, stream>>>(sorted, gbase, eidx, rowptr, dinv, n, e);
    k_gemm<<<(n + 63) / 64, 256, 0, stream>>>(x, WTs, dinv, h, n);
    k_gather<<<(n + 3) / 4, 256, 0, stream>>>(rowptr, eidx, h, dinv, bias, out, n);
}

// Round 12
// 284.287 us; speedup vs baseline: 1.0200x; 1.0200x over previous
//
#include <hip/hip_runtime.h>

#define C_IN 256
#define C_OUT 64
#define BSH 7                 // bucket = dst >> 7  (128 nodes/bucket)
#define NPB 128               // nodes per bucket
#define NB 1024               // max buckets (n <= 131072)
#define CHUNK 8192            // edges per binning block (LDS-staged multisplit)
#define RG 32                 // rows per row-group in kA2 (16*32=512 >= nbin=391)
#define SCAP 6144             // k_sort2 LDS stage capacity (lambda=4096, 32 sigma margin)

typedef short bf16x8 __attribute__((ext_vector_type(8)));
typedef float f32x4 __attribute__((ext_vector_type(4)));

__device__ __forceinline__ unsigned short f2bf(float f) {
    unsigned u = __builtin_bit_cast(unsigned, f);
    u = (u + 0x7FFFu + ((u >> 16) & 1u)) >> 16;
    return (unsigned short)u;
}
__device__ __forceinline__ float bflo(unsigned u) {
    return __builtin_bit_cast(float, u << 16);
}
__device__ __forceinline__ float bfhi(unsigned u) {
    return __builtin_bit_cast(float, u & 0xffff0000u);
}

// ---------------- per-(block,bucket) histogram table (+ fused WT transpose in block 0) ----------------
// WTs = bf16(W^T), XOR-swizzled content: element (row,k) at
// row*256 + ((k>>3) ^ (row&7))*8 + (k&7). Barrier-free extra work for
// threads <256 of block 0; WTs consumed only by k_gemm (4 launches later).
__global__ __launch_bounds__(1024) void k_hist2(const int* __restrict__ dst,
                                                int* __restrict__ table, int e,
                                                const float* __restrict__ W,
                                                unsigned short* __restrict__ WTs) {
    __shared__ int cnt[NB];
    cnt[threadIdx.x] = 0;
    __syncthreads();
    if (blockIdx.x == 0 && threadIdx.x < 256) {
#pragma unroll
        for (int i = 0; i < 16; ++i) {
            int f = i * 256 + threadIdx.x;   // float4 id over 256x64
            int k = f >> 4;
            int n4 = (f & 15) * 4;
            float4 v = ((const float4*)W)[f];
            int c = k >> 3, ci = k & 7;
            float vv[4] = {v.x, v.y, v.z, v.w};
#pragma unroll
            for (int r = 0; r < 4; ++r) {
                int row = n4 + r;
                WTs[row * 256 + ((c ^ (row & 7)) << 3) + ci] = f2bf(vv[r]);
            }
        }
    }
    int b0 = blockIdx.x * CHUNK;
#pragma unroll
    for (int k = 0; k < CHUNK / 1024; ++k) {
        int i = b0 + k * 1024 + threadIdx.x;
        if (i < e) atomicAdd(&cnt[dst[i] >> BSH], 1);
    }
    __syncthreads();
    table[(size_t)blockIdx.x * NB + threadIdx.x] = cnt[threadIdx.x];
}

// ---------------- column-wise exclusive scan, line-coalesced ----------------
__global__ __launch_bounds__(256) void kA2(int* __restrict__ table,
                                           int* __restrict__ tot, int nbin) {
    __shared__ int part[256];
    int t = threadIdx.x;
    int bc = t & 15, rg = t >> 4;
    int B = blockIdx.x * 16 + bc;
    int v[RG];
    int s = 0;
#pragma unroll
    for (int i = 0; i < RG; ++i) {
        int r = rg * RG + i;
        int x = (r < nbin) ? table[(size_t)r * NB + B] : 0;
        v[i] = s;
        s += x;
    }
    part[t] = s;
    __syncthreads();
#pragma unroll
    for (int off = 1; off < 16; off <<= 1) {
        int u = (rg >= off) ? part[t - off * 16] : 0;
        __syncthreads();
        part[t] += u;
        __syncthreads();
    }
    int incl = part[t];
    int base = incl - s;   // exclusive over row-groups
#pragma unroll
    for (int i = 0; i < RG; ++i) {
        int r = rg * RG + i;
        if (r < nbin) table[(size_t)r * NB + B] = base + v[i];
    }
    if (rg == 15) tot[B] = incl;
}

// ---------------- bucket totals -> compact gbase ----------------
__global__ __launch_bounds__(1024) void kB(const int* __restrict__ tot,
                                           int* __restrict__ gbase, int e) {
    __shared__ int l[NB];
    int t = threadIdx.x;
    int v = tot[t];
    l[t] = v;
    __syncthreads();
    for (int off = 1; off < NB; off <<= 1) {
        int u = (t >= off) ? l[t - off] : 0;
        __syncthreads();
        l[t] += u;
        __syncthreads();
    }
    gbase[t] = l[t] - v;  // exclusive
    if (t == NB - 1) gbase[NB] = e;
}

// ---------------- LDS-staged multisplit: bucket-contiguous coalesced writes ----------------
__global__ __launch_bounds__(1024) void k_bin2(const int* __restrict__ src,
                                               const int* __restrict__ dst,
                                               const int* __restrict__ table,
                                               const int* __restrict__ gbase,
                                               int* __restrict__ sorted, int e) {
    __shared__ int stage[CHUNK];            // 32 KB: packed values, bucket-sorted
    __shared__ unsigned short sbkt[CHUNK];  // 16 KB: bucket tag per stage slot
    __shared__ int lcnt[NB];                // counts, later reused as global base
    __shared__ int lsc[NB];                 // inclusive scan
    __shared__ int lbase[NB];               // exclusive scan
    int t = threadIdx.x;
    lcnt[t] = 0;
    __syncthreads();
    int b0 = blockIdx.x * CHUNK;

    int bb[CHUNK / 1024], pv[CHUNK / 1024], rk[CHUNK / 1024];
#pragma unroll
    for (int k = 0; k < CHUNK / 1024; ++k) {
        int i = b0 + k * 1024 + t;
        if (i < e) {
            int d = dst[i];
            bb[k] = d >> BSH;
            pv[k] = (src[i] << BSH) | (d & (NPB - 1));
            rk[k] = atomicAdd(&lcnt[bb[k]], 1);   // rank within (block,bucket)
        } else {
            bb[k] = -1;
        }
    }
    __syncthreads();
    lsc[t] = lcnt[t];
    __syncthreads();
    for (int off = 1; off < NB; off <<= 1) {
        int u = (t >= off) ? lsc[t - off] : 0;
        __syncthreads();
        lsc[t] += u;
        __syncthreads();
    }
    lbase[t] = lsc[t] - lcnt[t];
    __syncthreads();
    int tot = lsc[NB - 1];

    // scatter into LDS stage (bucket-sorted); also pre-load global bases
#pragma unroll
    for (int k = 0; k < CHUNK / 1024; ++k) {
        if (bb[k] >= 0) {
            int p = lbase[bb[k]] + rk[k];
            stage[p] = pv[k];
            sbkt[p] = (unsigned short)bb[k];
        }
    }
    lcnt[t] = gbase[t] + table[(size_t)blockIdx.x * NB + t];  // reuse as gb[bucket]
    __syncthreads();

    // coalesced sweep: consecutive j in same bucket -> consecutive global addrs
#pragma unroll
    for (int k = 0; k < CHUNK / 1024; ++k) {
        int j = k * 1024 + t;
        if (j < tot) {
            int B = sbkt[j];
            sorted[lcnt[B] + (j - lbase[B])] = stage[j];
        }
    }
}

// ---------------- in-bucket counting sort -> per-node CSR, plus dinv (512 thr) ----------------
__global__ __launch_bounds__(512) void k_sort2(const int* __restrict__ sorted,
                                               const int* __restrict__ gbase,
                                               int* __restrict__ eidx,
                                               int* __restrict__ rowptr,
                                               float* __restrict__ dinv, int n, int e) {
    __shared__ int cnt[NPB];
    __shared__ int sc[NPB];
    __shared__ int cur[NPB];
    __shared__ int sstage[SCAP];   // 24 KB
    int b = blockIdx.x;
    int node0 = b * NPB;
    int range = min(NPB, n - node0);
    int inbase = gbase[b];
    int m_b = gbase[b + 1] - inbase;
    bool fits = (m_b <= SCAP);
    if (threadIdx.x < NPB) cnt[threadIdx.x] = 0;
    if (fits)
        for (int j = threadIdx.x; j < m_b; j += 512) sstage[j] = sorted[inbase + j];
    __syncthreads();
    for (int j = threadIdx.x; j < m_b; j += 512) {
        int v = fits ? sstage[j] : sorted[inbase + j];
        atomicAdd(&cnt[v & (NPB - 1)], 1);
    }
    __syncthreads();
    if (threadIdx.x < NPB) sc[threadIdx.x] = cnt[threadIdx.x];
    __syncthreads();
    for (int off = 1; off < NPB; off <<= 1) {
        int t = (threadIdx.x < NPB && threadIdx.x >= off) ? sc[threadIdx.x - off] : 0;
        __syncthreads();
        if (threadIdx.x < NPB) sc[threadIdx.x] += t;
        __syncthreads();
    }
    if (threadIdx.x < NPB) {
        int excl = inbase + sc[threadIdx.x] - cnt[threadIdx.x];
        cur[threadIdx.x] = excl;
        if (threadIdx.x < range) {
            rowptr[node0 + threadIdx.x] = excl;
            dinv[node0 + threadIdx.x] = rsqrtf((float)(cnt[threadIdx.x] + 1));
        }
    }
    __syncthreads();
    for (int j = threadIdx.x; j < m_b; j += 512) {
        int v = fits ? sstage[j] : sorted[inbase + j];
        int pos = atomicAdd(&cur[v & (NPB - 1)], 1);
        eidx[pos] = v >> BSH;
    }
    if (b == 0 && threadIdx.x == 0) rowptr[n] = e;
}

// ---------------- h' = (x @ W) * dinv[row], bf16 MFMA (R6/R7 form -- best measured) ----------------
__global__ __launch_bounds__(256, 3) void k_gemm(const float* __restrict__ x,
                                                 const unsigned short* __restrict__ WTs,
                                                 const float* __restrict__ dinv,
                                                 unsigned short* __restrict__ h, int n) {
    __shared__ unsigned short Wl[64 * 256];   // 32 KB, swizzled content, linear layout

    const int t = threadIdx.x;
    const int lane = t & 63;
    const int wv = t >> 6;      // wave 0..3 -> A rows 16wv..16wv+15
    const int m = lane & 15;
    const int q = lane >> 4;
    const int mx = m & 7;

    // zero pad row h[n] (128 B) for k_gather's padded gathers
    if (blockIdx.x == 0 && t < 8)
        *(uint4*)&h[(size_t)n * C_OUT + t * 8] = make_uint4(0u, 0u, 0u, 0u);

    // -------- stage WTs -> Wl: 8 async direct-to-LDS copies
#pragma unroll
    for (int j = 0; j < 8; ++j) {
        const unsigned short* gsrc = WTs + j * 2048 + wv * 512 + lane * 8;  // 16 B/lane
        unsigned short* ldst = Wl + j * 2048 + wv * 512;                    // wave-uniform
        __builtin_amdgcn_global_load_lds(
            (const __attribute__((address_space(1))) unsigned int*)gsrc,
            (__attribute__((address_space(3))) unsigned int*)ldst, 16, 0, 0);
    }

    // -------- issue ALL 16 x-loads (inline asm: compiler cannot fold/serialize)
    int arow = blockIdx.x * 64 + 16 * wv + m;
    const float* xp = x + (size_t)(arow < n ? arow : 0) * C_IN + q * 8;
    float4 raw[16];
#pragma unroll
    for (int ks = 0; ks < 8; ++ks) {
        const float* p0 = xp + ks * 32;
        const float* p1 = xp + ks * 32 + 4;
        asm volatile("global_load_dwordx4 %0, %1, off" : "=v"(raw[2 * ks]) : "v"(p0));
        asm volatile("global_load_dwordx4 %0, %1, off" : "=v"(raw[2 * ks + 1]) : "v"(p1));
    }

    // -------- single drain point for x-loads AND the LDS staging
    asm volatile("s_waitcnt vmcnt(0)" ::: "memory");
    __builtin_amdgcn_sched_barrier(0);
    __syncthreads();

    float di[4];
#pragma unroll
    for (int r = 0; r < 4; ++r) {
        int gr = blockIdx.x * 64 + 16 * wv + q * 4 + r;
        di[r] = dinv[gr < n ? gr : 0];
    }

    bf16x8 A[8];
#pragma unroll
    for (int ks = 0; ks < 8; ++ks) {
        float4 v0 = raw[2 * ks];
        float4 v1 = raw[2 * ks + 1];
        bf16x8 a;
        a[0] = (short)f2bf(v0.x); a[1] = (short)f2bf(v0.y);
        a[2] = (short)f2bf(v0.z); a[3] = (short)f2bf(v0.w);
        a[4] = (short)f2bf(v1.x); a[5] = (short)f2bf(v1.y);
        a[6] = (short)f2bf(v1.z); a[7] = (short)f2bf(v1.w);
        A[ks] = a;
    }

    f32x4 acc[4];
#pragma unroll
    for (int nt = 0; nt < 4; ++nt) acc[nt] = (f32x4){0.f, 0.f, 0.f, 0.f};

#pragma unroll
    for (int ks = 0; ks < 8; ++ks) {
        int cs = ((ks * 4 + q) ^ mx) << 3;   // XOR-swizzled 16B slot within row
#pragma unroll
        for (int nt = 0; nt < 4; ++nt) {
            bf16x8 B = *(const bf16x8*)&Wl[(nt * 16 + m) * 256 + cs];
            acc[nt] = __builtin_amdgcn_mfma_f32_16x16x32_bf16(A[ks], B, acc[nt], 0, 0, 0);
        }
    }

#pragma unroll
    for (int r = 0; r < 4; ++r) {
        int gr = blockIdx.x * 64 + 16 * wv + q * 4 + r;
        if (gr < n) {
#pragma unroll
            for (int nt = 0; nt < 4; ++nt)
                h[(size_t)gr * C_OUT + nt * 16 + m] = f2bf(acc[nt][r] * di[r]);
        }
    }
}

// ---------------- gather: 1 wave/node, conditional 4/8 gathers, full drain (proven form) ----------------
// R11 core-dumped with staged vmcnt(4)/vmcnt(2) drains; revert to the R4-proven
// full-drain schedule (59.8us, passed twice). Conditional 4/8 avoids R10's
// pad-ACC waste.
#define GROUND(T, HV)                                                                   \
    {                                                                                   \
        int s_ = __shfl(eid, (T) * 8 + g, 64);                                          \
        const unsigned short* p_ = h + (size_t)s_ * C_OUT + c8;                         \
        asm volatile("global_load_dwordx4 %0, %1, off" : "=v"(HV) : "v"(p_));           \
    }
#define ACC8(HV)                                                                        \
    {                                                                                   \
        a0 += bflo(HV.x); a1 += bfhi(HV.x); a2 += bflo(HV.y); a3 += bfhi(HV.y);         \
        a4 += bflo(HV.z); a5 += bfhi(HV.z); a6 += bflo(HV.w); a7 += bfhi(HV.w);         \
    }

__global__ __launch_bounds__(256) void k_gather(const int* __restrict__ rowptr,
                                                const int* __restrict__ eidx,
                                                const unsigned short* __restrict__ h,
                                                const float* __restrict__ dinv,
                                                const float* __restrict__ bias,
                                                float* __restrict__ out, int n) {
    int node = blockIdx.x * 4 + (threadIdx.x >> 6);
    if (node >= n) return;
    int lane = threadIdx.x & 63;
    int g = lane >> 3;          // edge slot group 0..7
    int c8 = (lane & 7) * 8;    // channel base 0..56

    int beg = rowptr[node];
    int end = rowptr[node + 1];

    float a0 = 0.f, a1 = 0.f, a2 = 0.f, a3 = 0.f;
    float a4 = 0.f, a5 = 0.f, a6 = 0.f, a7 = 0.f;

    for (int j = beg; j < end; j += 64) {
        int idx = j + lane;
        int eid = (idx < end) ? eidx[idx] : n;   // pad -> zero row
        uint4 hv0, hv1, hv2, hv3, hv4, hv5, hv6, hv7;
        GROUND(0, hv0); GROUND(1, hv1); GROUND(2, hv2); GROUND(3, hv3);
        bool more = (end - j) > 32;              // wave-uniform
        if (more) { GROUND(4, hv4); GROUND(5, hv5); GROUND(6, hv6); GROUND(7, hv7); }
        asm volatile("s_waitcnt vmcnt(0)" ::: "memory");
        __builtin_amdgcn_sched_barrier(0);
        ACC8(hv0); ACC8(hv1); ACC8(hv2); ACC8(hv3);
        if (more) { ACC8(hv4); ACC8(hv5); ACC8(hv6); ACC8(hv7); }
    }

#pragma unroll
    for (int off = 8; off < 64; off <<= 1) {
        a0 += __shfl_xor(a0, off, 64); a1 += __shfl_xor(a1, off, 64);
        a2 += __shfl_xor(a2, off, 64); a3 += __shfl_xor(a3, off, 64);
        a4 += __shfl_xor(a4, off, 64); a5 += __shfl_xor(a5, off, 64);
        a6 += __shfl_xor(a6, off, 64); a7 += __shfl_xor(a7, off, 64);
    }
    if (g == 0) {
        float di = dinv[node];
        uint4 sv = *(const uint4*)&h[(size_t)node * C_OUT + c8];
        float4 b0 = *(const float4*)&bias[c8];
        float4 b1 = *(const float4*)&bias[c8 + 4];
        float4 o0, o1;
        o0.x = (a0 + bflo(sv.x)) * di + b0.x;
        o0.y = (a1 + bfhi(sv.x)) * di + b0.y;
        o0.z = (a2 + bflo(sv.y)) * di + b0.z;
        o0.w = (a3 + bfhi(sv.y)) * di + b0.w;
        o1.x = (a4 + bflo(sv.z)) * di + b1.x;
        o1.y = (a5 + bfhi(sv.z)) * di + b1.y;
        o1.z = (a6 + bflo(sv.w)) * di + b1.z;
        o1.w = (a7 + bfhi(sv.w)) * di + b1.w;
        *(float4*)&out[(size_t)node * C_OUT + c8] = o0;
        *(float4*)&out[(size_t)node * C_OUT + c8 + 4] = o1;
    }
}

extern "C" void kernel_launch(void* const* d_in, const int* in_sizes, int n_in,
                              void* d_out, int out_size, void* d_ws, size_t ws_size,
                              hipStream_t stream) {
    const float* x = (const float*)d_in[0];
    const int* ei = (const int*)d_in[1];
    const float* W = (const float*)d_in[2];
    const float* bias = (const float*)d_in[3];
    float* out = (float*)d_out;

    const int n = in_sizes[0] / C_IN;  // 100000
    const int e = in_sizes[1] / 2;     // 3200000
    const int* src = ei;
    const int* dst = ei + e;

    const int nbin = (e + CHUNK - 1) / CHUNK;   // 391 (<= 16*RG = 512)
    const int nbuck = (n + NPB - 1) / NPB;      // 782

    char* w = (char*)d_ws;
    unsigned short* h = (unsigned short*)w;  w += ((size_t)n + 1) * C_OUT * 2; // 12.8 MB + pad row
    int* sorted = (int*)w;                   w += (size_t)e * 4;           // 12.8 MB
    int* eidx = (int*)w;                     w += (size_t)e * 4;           // 12.8 MB
    float* dinv = (float*)w;                 w += (size_t)n * 4;
    int* rowptr = (int*)w;                   w += (size_t)(n + 1) * 4;
    int* table = (int*)w;                    w += (size_t)nbin * NB * 4;   // 1.6 MB
    int* tot = (int*)w;                      w += NB * 4;
    int* gbase = (int*)w;                    w += (NB + 1) * 4;
    unsigned short* WTs = (unsigned short*)w; w += (size_t)C_OUT * C_IN * 2; // 32 KB

    k_hist2<<<nbin, 1024, 0, stream>>>(dst, table, e, W, WTs);
    kA2<<<NB / 16, 256, 0, stream>>>(table, tot, nbin);
    kB<<<1, 1024, 0, stream>>>(tot, gbase, e);
    k_bin2<<<nbin, 1024, 0, stream>>>(src, dst, table, gbase, sorted, e);
    k_sort2<<<nbuck, 512, 0, stream>>>(sorted, gbase, eidx, rowptr, dinv, n, e);
    k_gemm<<<(n + 63) / 64, 256, 0, stream>>>(x, WTs, dinv, h, n);
    k_gather<<<(n + 3) / 4, 256, 0, stream>>>(rowptr, eidx, h, dinv, bias, out, n);
}